// Round 15
// baseline (58.056 us; speedup 1.0000x reference)
//
#include <hip/hip_runtime.h>
#include <hip/hip_bf16.h>

#define BATCH 32
#define WW 900
#define CCH 256
#define KHALF 128     // K columns per block (K-split x2)
#define MSTRIP 256    // M rows per block (4 waves x 64 rows)
#define NCHUNK 64     // B rows staged per chunk
#define NCHUNKS 15    // 15*64 = 960 >= 900

typedef __bf16 bf16x8 __attribute__((ext_vector_type(8)));
typedef __bf16 bf16x4 __attribute__((ext_vector_type(4)));
typedef float f32x4 __attribute__((ext_vector_type(4)));

// ws layout (floats): sums [0, 64*segs*256); inv [INV15_OFF or INV4_OFF, +16384)
#define INV15_OFF 245760
#define INV4_OFF  65536

// ---------------- norm pass 1: partial sums of squares (+ fused out-zeroing) ----------------
__global__ void nc_norm_partial(const float* __restrict__ x1,
                                const float* __restrict__ x2,
                                float* __restrict__ sums,
                                float* __restrict__ out, int out_n,
                                int segs, int rowsper) {
    int blk = blockIdx.x;
    int oz = blk * 256 + threadIdx.x;
    if (oz < out_n) out[oz] = 0.f;
    int seg = blk % segs;
    int b = (blk / segs) & 31;
    int which = blk / (segs * 32);
    const float* x = which ? x2 : x1;
    int c = threadIdx.x;
    int r0 = seg * rowsper;
    int r1 = r0 + rowsper;
    if (r1 > WW) r1 = WW;
    const float* p = x + ((size_t)b * WW + r0) * CCH + c;
    float s = 0.f;
    #pragma unroll 4
    for (int w = 0; w < r1 - r0; ++w) {
        float v = p[(size_t)w * CCH];
        s = fmaf(v, v, s);
    }
    sums[(((size_t)(which * 32 + b)) * segs + seg) * CCH + c] = s;
}

// ---------------- norm pass 2: inv = rsqrt(max(sum, eps)) ----------------
template <int SEGS>
__global__ void nc_norm_finalize(float* __restrict__ ws, float* __restrict__ inv) {
    int i = blockIdx.x * 256 + threadIdx.x;
    int c = i & 255;
    int wb = i >> 8;
    const float* s = ws + (size_t)wb * SEGS * CCH + c;
    float t = 0.f;
    #pragma unroll
    for (int q = 0; q < SEGS; ++q) t += s[(size_t)q * CCH];
    inv[i] = rsqrtf(fmaxf(t, 1e-12f));
}

// ---------------- main: GEMM + diagonal reduction, 64-row waves (mt=4) ----------------
// grid = 256: b = blockIdx&31, strip = (blockIdx>>5)&3, kh = blockIdx>>7. 1 block/CU.
// Each B-fragment read now feeds 4 MFMAs (was 2): GEMM LDS traffic per CU halves.
// Epilogue = R13's proven 32-row epilogue run twice per wave (virtual waves vw=2w+h),
// each with its own scratch region (no WAR). Fold formula identical to R13 (verified).
__global__ __launch_bounds__(256, 1)
void nc_corr(const float* __restrict__ x1,
             const float* __restrict__ x2,
             const float* __restrict__ invp,
             float* __restrict__ out) {
    __shared__ __bf16 Abuf[MSTRIP * KHALF];       // 64 KB; scratch[8][16][97] after hoist
    __shared__ __bf16 Bbuf[2][NCHUNK * KHALF];    // 2 x 16 KB
    __shared__ float diag[2][8][96];              // 6 KB
    __shared__ float partial[WW];                 // 3.6 KB

    float (*scratch)[16][97] = (float (*)[16][97])Abuf;   // 12416 dwords <= 16384

    const int tid = threadIdx.x;
    const int b = blockIdx.x & 31;
    const int strip = (blockIdx.x >> 5) & 3;
    const int kh = blockIdx.x >> 7;
    const int m0 = strip * MSTRIP;
    const int k0 = kh * KHALF;

    const float* __restrict__ inv1 = invp + b * CCH + k0;
    const float* __restrict__ inv2 = invp + (BATCH + b) * CCH + k0;
    const float* __restrict__ x1b = x1 + (size_t)b * WW * CCH + k0;
    const float* __restrict__ x2b = x2 + (size_t)b * WW * CCH + k0;

    const int lane = tid & 63;
    const int wave = tid >> 6;     // rows m0 + wave*64 .. +63
    const int fr = lane & 15;
    const int fq = lane >> 4;

    // coalesced staging coords
    const int sr = tid >> 5;       // 0..7
    const int sg = tid & 31;       // 0..31

    // ---- B staging: coalesced, 8 float4 per thread per 64-row chunk ----
    const float4 ivB = *(const float4*)(inv2 + sg * 4);
    float4 st[8];

    auto loadB = [&](int chunk) {
        #pragma unroll
        for (int k = 0; k < 8; ++k) {
            const int row = chunk * NCHUNK + sr + 8 * k;
            st[k] = (row < WW) ? *(const float4*)(x2b + (size_t)row * CCH + sg * 4)
                               : make_float4(0.f, 0.f, 0.f, 0.f);
        }
    };
    auto writeB = [&](int buf) {
        #pragma unroll
        for (int k = 0; k < 8; ++k) {
            const int row = sr + 8 * k;        // 0..63
            float4 f = st[k];
            bf16x4 v = { (__bf16)(f.x * ivB.x), (__bf16)(f.y * ivB.y),
                         (__bf16)(f.z * ivB.z), (__bf16)(f.w * ivB.w) };
            *(bf16x4*)(&Bbuf[buf][row * KHALF + (((sg >> 1) ^ sr) << 3) + (sg & 1) * 4]) = v;
        }
    };

    loadB(0);

    // ---- Stage A once: 256 rows x 128 cols, coalesced, normalized, swizzled ----
    {
        float4 iv1 = *(const float4*)(inv1 + sg * 4);
        #pragma unroll
        for (int k = 0; k < 32; ++k) {
            const int row = sr + 8 * k;        // 0..255
            const int m = m0 + row;
            float4 f = make_float4(0.f, 0.f, 0.f, 0.f);
            if (m < WW) f = *(const float4*)(x1b + (size_t)m * CCH + sg * 4);
            bf16x4 v = { (__bf16)(f.x * iv1.x), (__bf16)(f.y * iv1.y),
                         (__bf16)(f.z * iv1.z), (__bf16)(f.w * iv1.w) };
            *(bf16x4*)(&Abuf[row * KHALF + (((sg >> 1) ^ (row & 7)) << 3) + (sg & 1) * 4]) = v;
        }
    }

    for (int i = tid; i < WW; i += 256) partial[i] = 0.f;
    writeB(0);
    __syncthreads();   // A staged, B chunk0 staged, partial zeroed

    // ---- A fragments: LDS -> registers ONCE (64 VGPR), pinned against re-sink ----
    bf16x8 afm[4][4];
    #pragma unroll
    for (int mt = 0; mt < 4; ++mt)
        #pragma unroll
        for (int kk = 0; kk < 4; ++kk) {
            const int row = wave * 64 + mt * 16 + fr;
            const int g = (kk * 4 + fq) ^ (row & 7);
            afm[mt][kk] = *(const bf16x8*)(&Abuf[row * KHALF + g * 8]);
        }
    #pragma unroll
    for (int mt = 0; mt < 4; ++mt)
        #pragma unroll
        for (int kk = 0; kk < 4; ++kk)
            asm volatile("" : "+v"(afm[mt][kk]));

    __syncthreads();   // ALL waves done reading Abuf -> safe to reuse as scratch

    // wave-local zero of this wave's two scratch regions (vw = 2*wave, 2*wave+1)
    {
        float* sw = (float*)&scratch[2 * wave][0][0];
        for (int i = lane; i < 2 * 16 * 97; i += 64) sw[i] = 0.f;
    }

    int cur = 0;
    for (int chunk = 0; chunk < NCHUNKS; ++chunk) {
        if (chunk + 1 < NCHUNKS) {
            loadB(chunk + 1);                        // issue early (T14)
            __builtin_amdgcn_sched_barrier(0);       // lock prefetch position (anti-sink)
        }

        f32x4 acc[4][4];
        #pragma unroll
        for (int mt = 0; mt < 4; ++mt)
            #pragma unroll
            for (int nt = 0; nt < 4; ++nt)
                acc[mt][nt] = (f32x4){0.f, 0.f, 0.f, 0.f};

        #pragma unroll
        for (int kk = 0; kk < 4; ++kk) {
            bf16x8 bfr[4];
            #pragma unroll
            for (int nt = 0; nt < 4; ++nt) {
                const int row = nt * 16 + fr;
                const int g = (kk * 4 + fq) ^ (row & 7);
                bfr[nt] = *(const bf16x8*)(&Bbuf[cur][row * KHALF + g * 8]);
            }
            #pragma unroll
            for (int mt = 0; mt < 4; ++mt)
                #pragma unroll
                for (int nt = 0; nt < 4; ++nt)
                    acc[mt][nt] = __builtin_amdgcn_mfma_f32_16x16x32_bf16(
                        afm[mt][kk], bfr[nt], acc[mt][nt], 0, 0, 0);
        }

        // ---- epilogue: two 32-row halves, each EXACTLY the proven R13 epilogue ----
        #pragma unroll
        for (int h = 0; h < 2; ++h) {
            const int vw = 2 * wave + h;
            {
                f32x4 c0 = acc[2*h+0][3];                        // ddn = 0
                f32x4 c1 = acc[2*h+0][2] + acc[2*h+1][3];        // ddn = 1
                f32x4 c2 = acc[2*h+0][1] + acc[2*h+1][2];        // ddn = 2
                f32x4 c3 = acc[2*h+0][0] + acc[2*h+1][1];        // ddn = 3
                f32x4 c4 = acc[2*h+1][0];                        // ddn = 4
                const int mub = 4 * fq;
                #pragma unroll
                for (int r = 0; r < 4; ++r) {
                    const int mu = mub + r;
                    const int drb = mu - fr + 15;                // 0..30
                    scratch[vw][mu][drb]      = c0[r];
                    scratch[vw][mu][drb + 16] = c1[r];
                    scratch[vw][mu][drb + 32] = c2[r];
                    scratch[vw][mu][drb + 48] = c3[r];
                    scratch[vw][mu][drb + 64] = c4[r];
                }
            }
            // per-vw row-sum (unconditional paired reads; OOB-by-design reads discarded)
            {
                float s = 0.f, s2 = 0.f;
                #pragma unroll
                for (int m = 0; m < 16; ++m) {
                    s  += scratch[vw][m][lane];
                    s2 += scratch[vw][m][64 + lane];
                }
                diag[chunk & 1][vw][lane] = s;
                if (lane < 31) diag[chunk & 1][vw][64 + lane] = s2;
            }
        }

        if (chunk + 1 < NCHUNKS) writeB(cur ^ 1);
        __syncthreads();

        // ---- ownership fold: t = 32*vw + dr in [0,319); j unique per t ----
        {
            const int par = chunk & 1;
            #pragma unroll
            for (int pass = 0; pass < 2; ++pass) {
                const int t = tid + pass * 256;
                if (pass == 0 || tid < 63) {
                    float s = 0.f;
                    #pragma unroll
                    for (int w = 0; w < 8; ++w) {
                        const int dr = t - 32 * w;
                        if (dr >= 0 && dr < 95) s += diag[par][w][dr];
                    }
                    int v = m0 - 64 * chunk + t + 1287;   // in [391, 2373]
                    if (v >= 1800) v -= 900;
                    if (v >= 900) v -= 900;
                    partial[v] += s;
                }
            }
        }
        cur ^= 1;
    }

    __syncthreads();
    for (int i = tid; i < WW; i += 256)
        unsafeAtomicAdd(&out[(size_t)b * WW + i], partial[i]);  // 8 blocks per batch
}

extern "C" void kernel_launch(void* const* d_in, const int* in_sizes, int n_in,
                              void* d_out, int out_size, void* d_ws, size_t ws_size,
                              hipStream_t stream) {
    const float* x1 = (const float*)d_in[0];
    const float* x2 = (const float*)d_in[1];
    float* out = (float*)d_out;
    float* ws = (float*)d_ws;

    const size_t need15 = (size_t)(INV15_OFF + 16384) * sizeof(float);  // ~1.05 MB
    if (ws_size >= need15) {
        const int segs = 15, rowsper = 60;
        nc_norm_partial<<<2 * 32 * segs, 256, 0, stream>>>(x1, x2, ws, out, out_size, segs, rowsper);
        nc_norm_finalize<15><<<64, 256, 0, stream>>>(ws, ws + INV15_OFF);
        nc_corr<<<256, 256, 0, stream>>>(x1, x2, ws + INV15_OFF, out);
    } else {
        const int segs = 4, rowsper = 225;
        nc_norm_partial<<<2 * 32 * segs, 256, 0, stream>>>(x1, x2, ws, out, out_size, segs, rowsper);
        nc_norm_finalize<4><<<64, 256, 0, stream>>>(ws, ws + INV4_OFF);
        nc_corr<<<256, 256, 0, stream>>>(x1, x2, ws + INV4_OFF, out);
    }
}

// Round 16
// 58.035 us; speedup vs baseline: 1.0004x; 1.0004x over previous
//
#include <hip/hip_runtime.h>
#include <hip/hip_bf16.h>

#define BATCH 32
#define WW 900
#define CCH 256
#define KHALF 128     // K columns per block (K-split x2)
#define MSTRIP 256    // M rows per block (4 waves x 64 rows)
#define NCHUNK 64     // B rows staged per chunk
#define NCHUNKS 15    // 15*64 = 960 >= 900

typedef __bf16 bf16x8 __attribute__((ext_vector_type(8)));
typedef __bf16 bf16x4 __attribute__((ext_vector_type(4)));
typedef float f32x4 __attribute__((ext_vector_type(4)));

// ws layout (floats): sums [0, 64*segs*256); inv [INV15_OFF or INV4_OFF, +16384)
#define INV15_OFF 245760
#define INV4_OFF  65536

// ---------------- norm pass 1: partial sums of squares (+ fused out-zeroing) ----------------
__global__ void nc_norm_partial(const float* __restrict__ x1,
                                const float* __restrict__ x2,
                                float* __restrict__ sums,
                                float* __restrict__ out, int out_n,
                                int segs, int rowsper) {
    int blk = blockIdx.x;
    int oz = blk * 256 + threadIdx.x;
    if (oz < out_n) out[oz] = 0.f;
    int seg = blk % segs;
    int b = (blk / segs) & 31;
    int which = blk / (segs * 32);
    const float* x = which ? x2 : x1;
    int c = threadIdx.x;
    int r0 = seg * rowsper;
    int r1 = r0 + rowsper;
    if (r1 > WW) r1 = WW;
    const float* p = x + ((size_t)b * WW + r0) * CCH + c;
    float s = 0.f;
    #pragma unroll 4
    for (int w = 0; w < r1 - r0; ++w) {
        float v = p[(size_t)w * CCH];
        s = fmaf(v, v, s);
    }
    sums[(((size_t)(which * 32 + b)) * segs + seg) * CCH + c] = s;
}

// ---------------- norm pass 2: inv = rsqrt(max(sum, eps)) ----------------
template <int SEGS>
__global__ void nc_norm_finalize(float* __restrict__ ws, float* __restrict__ inv) {
    int i = blockIdx.x * 256 + threadIdx.x;
    int c = i & 255;
    int wb = i >> 8;
    const float* s = ws + (size_t)wb * SEGS * CCH + c;
    float t = 0.f;
    #pragma unroll
    for (int q = 0; q < SEGS; ++q) t += s[(size_t)q * CCH];
    inv[i] = rsqrtf(fmaxf(t, 1e-12f));
}

// ---------------- main: GEMM + diagonal reduction, 64-row waves (mt=4) ----------------
// grid = 256: b = blockIdx&31, strip = (blockIdx>>5)&3, kh = blockIdx>>7. 1 block/CU.
// Each B-fragment read now feeds 4 MFMAs (was 2): GEMM LDS traffic per CU halves.
// Epilogue = R13's proven 32-row epilogue run twice per wave (virtual waves vw=2w+h),
// each with its own scratch region (no WAR). Fold formula identical to R13 (verified).
__global__ __launch_bounds__(256, 1)
void nc_corr(const float* __restrict__ x1,
             const float* __restrict__ x2,
             const float* __restrict__ invp,
             float* __restrict__ out) {
    __shared__ __bf16 Abuf[MSTRIP * KHALF];       // 64 KB; scratch[8][16][97] after hoist
    __shared__ __bf16 Bbuf[2][NCHUNK * KHALF];    // 2 x 16 KB
    __shared__ float diag[2][8][96];              // 6 KB
    __shared__ float partial[WW];                 // 3.6 KB

    float (*scratch)[16][97] = (float (*)[16][97])Abuf;   // 12416 dwords <= 16384

    const int tid = threadIdx.x;
    const int b = blockIdx.x & 31;
    const int strip = (blockIdx.x >> 5) & 3;
    const int kh = blockIdx.x >> 7;
    const int m0 = strip * MSTRIP;
    const int k0 = kh * KHALF;

    const float* __restrict__ inv1 = invp + b * CCH + k0;
    const float* __restrict__ inv2 = invp + (BATCH + b) * CCH + k0;
    const float* __restrict__ x1b = x1 + (size_t)b * WW * CCH + k0;
    const float* __restrict__ x2b = x2 + (size_t)b * WW * CCH + k0;

    const int lane = tid & 63;
    const int wave = tid >> 6;     // rows m0 + wave*64 .. +63
    const int fr = lane & 15;
    const int fq = lane >> 4;

    // coalesced staging coords
    const int sr = tid >> 5;       // 0..7
    const int sg = tid & 31;       // 0..31

    // ---- B staging: coalesced, 8 float4 per thread per 64-row chunk ----
    const float4 ivB = *(const float4*)(inv2 + sg * 4);
    float4 st[8];

    auto loadB = [&](int chunk) {
        #pragma unroll
        for (int k = 0; k < 8; ++k) {
            const int row = chunk * NCHUNK + sr + 8 * k;
            st[k] = (row < WW) ? *(const float4*)(x2b + (size_t)row * CCH + sg * 4)
                               : make_float4(0.f, 0.f, 0.f, 0.f);
        }
    };
    auto writeB = [&](int buf) {
        #pragma unroll
        for (int k = 0; k < 8; ++k) {
            const int row = sr + 8 * k;        // 0..63
            float4 f = st[k];
            bf16x4 v = { (__bf16)(f.x * ivB.x), (__bf16)(f.y * ivB.y),
                         (__bf16)(f.z * ivB.z), (__bf16)(f.w * ivB.w) };
            *(bf16x4*)(&Bbuf[buf][row * KHALF + (((sg >> 1) ^ sr) << 3) + (sg & 1) * 4]) = v;
        }
    };

    loadB(0);

    // ---- Stage A once: 256 rows x 128 cols, coalesced, normalized, swizzled ----
    {
        float4 iv1 = *(const float4*)(inv1 + sg * 4);
        #pragma unroll
        for (int k = 0; k < 32; ++k) {
            const int row = sr + 8 * k;        // 0..255
            const int m = m0 + row;
            float4 f = make_float4(0.f, 0.f, 0.f, 0.f);
            if (m < WW) f = *(const float4*)(x1b + (size_t)m * CCH + sg * 4);
            bf16x4 v = { (__bf16)(f.x * iv1.x), (__bf16)(f.y * iv1.y),
                         (__bf16)(f.z * iv1.z), (__bf16)(f.w * iv1.w) };
            *(bf16x4*)(&Abuf[row * KHALF + (((sg >> 1) ^ (row & 7)) << 3) + (sg & 1) * 4]) = v;
        }
    }

    for (int i = tid; i < WW; i += 256) partial[i] = 0.f;
    writeB(0);
    __syncthreads();   // A staged, B chunk0 staged, partial zeroed

    // ---- A fragments: LDS -> registers ONCE (64 VGPR), pinned against re-sink ----
    bf16x8 afm[4][4];
    #pragma unroll
    for (int mt = 0; mt < 4; ++mt)
        #pragma unroll
        for (int kk = 0; kk < 4; ++kk) {
            const int row = wave * 64 + mt * 16 + fr;
            const int g = (kk * 4 + fq) ^ (row & 7);
            afm[mt][kk] = *(const bf16x8*)(&Abuf[row * KHALF + g * 8]);
        }
    #pragma unroll
    for (int mt = 0; mt < 4; ++mt)
        #pragma unroll
        for (int kk = 0; kk < 4; ++kk)
            asm volatile("" : "+v"(afm[mt][kk]));

    __syncthreads();   // ALL waves done reading Abuf -> safe to reuse as scratch

    // wave-local zero of this wave's two scratch regions (vw = 2*wave, 2*wave+1)
    {
        float* sw = (float*)&scratch[2 * wave][0][0];
        for (int i = lane; i < 2 * 16 * 97; i += 64) sw[i] = 0.f;
    }

    int cur = 0;
    for (int chunk = 0; chunk < NCHUNKS; ++chunk) {
        if (chunk + 1 < NCHUNKS) {
            loadB(chunk + 1);                        // issue early (T14)
            __builtin_amdgcn_sched_barrier(0);       // lock prefetch position (anti-sink)
        }

        f32x4 acc[4][4];
        #pragma unroll
        for (int mt = 0; mt < 4; ++mt)
            #pragma unroll
            for (int nt = 0; nt < 4; ++nt)
                acc[mt][nt] = (f32x4){0.f, 0.f, 0.f, 0.f};

        #pragma unroll
        for (int kk = 0; kk < 4; ++kk) {
            bf16x8 bfr[4];
            #pragma unroll
            for (int nt = 0; nt < 4; ++nt) {
                const int row = nt * 16 + fr;
                const int g = (kk * 4 + fq) ^ (row & 7);
                bfr[nt] = *(const bf16x8*)(&Bbuf[cur][row * KHALF + g * 8]);
            }
            #pragma unroll
            for (int mt = 0; mt < 4; ++mt)
                #pragma unroll
                for (int nt = 0; nt < 4; ++nt)
                    acc[mt][nt] = __builtin_amdgcn_mfma_f32_16x16x32_bf16(
                        afm[mt][kk], bfr[nt], acc[mt][nt], 0, 0, 0);
        }

        // ---- epilogue: two 32-row halves, each EXACTLY the proven R13 epilogue ----
        #pragma unroll
        for (int h = 0; h < 2; ++h) {
            const int vw = 2 * wave + h;
            {
                f32x4 c0 = acc[2*h+0][3];                        // ddn = 0
                f32x4 c1 = acc[2*h+0][2] + acc[2*h+1][3];        // ddn = 1
                f32x4 c2 = acc[2*h+0][1] + acc[2*h+1][2];        // ddn = 2
                f32x4 c3 = acc[2*h+0][0] + acc[2*h+1][1];        // ddn = 3
                f32x4 c4 = acc[2*h+1][0];                        // ddn = 4
                const int mub = 4 * fq;
                #pragma unroll
                for (int r = 0; r < 4; ++r) {
                    const int mu = mub + r;
                    const int drb = mu - fr + 15;                // 0..30
                    scratch[vw][mu][drb]      = c0[r];
                    scratch[vw][mu][drb + 16] = c1[r];
                    scratch[vw][mu][drb + 32] = c2[r];
                    scratch[vw][mu][drb + 48] = c3[r];
                    scratch[vw][mu][drb + 64] = c4[r];
                }
            }
            // per-vw row-sum (unconditional paired reads; OOB-by-design reads discarded)
            {
                float s = 0.f, s2 = 0.f;
                #pragma unroll
                for (int m = 0; m < 16; ++m) {
                    s  += scratch[vw][m][lane];
                    s2 += scratch[vw][m][64 + lane];
                }
                diag[chunk & 1][vw][lane] = s;
                if (lane < 31) diag[chunk & 1][vw][64 + lane] = s2;
            }
        }

        if (chunk + 1 < NCHUNKS) writeB(cur ^ 1);
        __syncthreads();

        // ---- ownership fold: t = 32*vw + dr in [0,319); j unique per t ----
        {
            const int par = chunk & 1;
            #pragma unroll
            for (int pass = 0; pass < 2; ++pass) {
                const int t = tid + pass * 256;
                if (pass == 0 || tid < 63) {
                    float s = 0.f;
                    #pragma unroll
                    for (int w = 0; w < 8; ++w) {
                        const int dr = t - 32 * w;
                        if (dr >= 0 && dr < 95) s += diag[par][w][dr];
                    }
                    int v = m0 - 64 * chunk + t + 1287;   // in [391, 2373]
                    if (v >= 1800) v -= 900;
                    if (v >= 900) v -= 900;
                    partial[v] += s;
                }
            }
        }
        cur ^= 1;
    }

    __syncthreads();
    for (int i = tid; i < WW; i += 256)
        unsafeAtomicAdd(&out[(size_t)b * WW + i], partial[i]);  // 8 blocks per batch
}

extern "C" void kernel_launch(void* const* d_in, const int* in_sizes, int n_in,
                              void* d_out, int out_size, void* d_ws, size_t ws_size,
                              hipStream_t stream) {
    const float* x1 = (const float*)d_in[0];
    const float* x2 = (const float*)d_in[1];
    float* out = (float*)d_out;
    float* ws = (float*)d_ws;

    const size_t need15 = (size_t)(INV15_OFF + 16384) * sizeof(float);  // ~1.05 MB
    if (ws_size >= need15) {
        const int segs = 15, rowsper = 60;
        nc_norm_partial<<<2 * 32 * segs, 256, 0, stream>>>(x1, x2, ws, out, out_size, segs, rowsper);
        nc_norm_finalize<15><<<64, 256, 0, stream>>>(ws, ws + INV15_OFF);
        nc_corr<<<256, 256, 0, stream>>>(x1, x2, ws + INV15_OFF, out);
    } else {
        const int segs = 4, rowsper = 225;
        nc_norm_partial<<<2 * 32 * segs, 256, 0, stream>>>(x1, x2, ws, out, out_size, segs, rowsper);
        nc_norm_finalize<4><<<64, 256, 0, stream>>>(ws, ws + INV4_OFF);
        nc_corr<<<256, 256, 0, stream>>>(x1, x2, ws + INV4_OFF, out);
    }
}